// Round 1
// baseline (631.850 us; speedup 1.0000x reference)
//
#include <hip/hip_runtime.h>
#include <hip/hip_bf16.h>

#define K_DIM 4096
#define N_DIM 11008
#define GROUP 128
#define BM 128
#define BN 128
#define BK 32
#define LDSS 40  // LDS row stride in bf16 elems: 32 + 8 pad (80B, keeps 16B alignment)

typedef __attribute__((ext_vector_type(8))) __bf16 bf16x8;
typedef __attribute__((ext_vector_type(4))) float f32x4;

static __device__ inline __bf16 f2bf(float f) { return (__bf16)f; }

__global__ __launch_bounds__(256) void gptq_gemm_kernel(
    const float* __restrict__ x,      // [M, K] fp32
    const int*   __restrict__ qw,     // [K/8, N] int32 (8 x int4 along K)
    const int*   __restrict__ qz,     // [K/128, N/8] int32 (8 x int4 along N)
    const float* __restrict__ sc,     // [K/128, N] fp32
    const float* __restrict__ bias,   // [N] fp32
    float*       __restrict__ out)    // [M, N] fp32
{
    __shared__ __align__(16) __bf16 Asm[BM][LDSS];
    __shared__ __align__(16) __bf16 Bsm[BN][LDSS];   // stored [n][k]

    const int tid  = threadIdx.x;
    const int lane = tid & 63;
    const int wid  = tid >> 6;            // 4 waves: 2x2 of 64x64 sub-tiles
    const int m0 = blockIdx.y * BM;
    const int n0 = blockIdx.x * BN;
    const int wm = (wid >> 1) * 64;
    const int wn = (wid & 1) * 64;

    f32x4 acc[4][4];
    #pragma unroll
    for (int i = 0; i < 4; ++i)
        #pragma unroll
        for (int j = 0; j < 4; ++j) acc[i][j] = (f32x4){0.f, 0.f, 0.f, 0.f};

    // A staging: thread -> (row a_m and a_m+64, 8-float chunk a_h)
    const int a_m = tid >> 2;             // 0..63
    const int a_h = tid & 3;              // 0..3, chunk of 8 floats
    // B staging: thread -> (col b_n, packed-word rows b_k8 and b_k8+2)
    const int b_n  = tid & 127;
    const int b_k8 = tid >> 7;            // 0 or 1
    const int ng   = n0 + b_n;            // global n for this thread's B column
    const int zsh  = (ng & 7) * 4;

    // MFMA fragment addressing
    const int fr = lane & 15;             // row (A) / col (B) within 16
    const int fc = lane >> 4;             // k-chunk of 8

    for (int k0 = 0; k0 < K_DIM; k0 += BK) {
        const int g = k0 >> 7;            // quant group (BK=32 divides GROUP=128)

        // ---- global loads to registers ----
        const float* xa = x + (size_t)(m0 + a_m) * K_DIM + k0 + a_h * 8;
        f32x4 a0 = *(const f32x4*)xa;
        f32x4 a1 = *(const f32x4*)(xa + 4);
        const float* xb = xa + (size_t)64 * K_DIM;
        f32x4 a2 = *(const f32x4*)xb;
        f32x4 a3 = *(const f32x4*)(xb + 4);

        const int kb = (k0 >> 3) + b_k8;  // packed qweight row
        const int w0 = qw[(size_t)kb * N_DIM + ng];
        const int w1 = qw[(size_t)(kb + 2) * N_DIM + ng];
        const float s = sc[(size_t)g * N_DIM + ng];
        const int   zword = qz[(size_t)g * (N_DIM / 8) + (ng >> 3)];
        const float nzs = -(float)((zword >> zsh) & 15) * s;   // -z*s (fma form)

        __syncthreads();   // previous iteration's LDS reads complete

        // ---- A: fp32 -> bf16, two b128 writes ----
        bf16x8 av0, av1;
        #pragma unroll
        for (int j = 0; j < 4; ++j) {
            av0[j]     = f2bf(a0[j]);
            av0[j + 4] = f2bf(a1[j]);
            av1[j]     = f2bf(a2[j]);
            av1[j + 4] = f2bf(a3[j]);
        }
        *(bf16x8*)&Asm[a_m][a_h * 8]      = av0;
        *(bf16x8*)&Asm[a_m + 64][a_h * 8] = av1;

        // ---- B: unpack int4, dequant (q*s - z*s), two b128 writes ----
        bf16x8 bv0, bv1;
        #pragma unroll
        for (int j = 0; j < 8; ++j) {
            bv0[j] = f2bf(fmaf((float)((w0 >> (4 * j)) & 15), s, nzs));
            bv1[j] = f2bf(fmaf((float)((w1 >> (4 * j)) & 15), s, nzs));
        }
        *(bf16x8*)&Bsm[b_n][b_k8 * 8]       = bv0;
        *(bf16x8*)&Bsm[b_n][(b_k8 + 2) * 8] = bv1;

        __syncthreads();

        // ---- fragments + MFMA ----
        bf16x8 af[4], bfr[4];
        #pragma unroll
        for (int i = 0; i < 4; ++i)
            af[i] = *(const bf16x8*)&Asm[wm + i * 16 + fr][fc * 8];
        #pragma unroll
        for (int j = 0; j < 4; ++j)
            bfr[j] = *(const bf16x8*)&Bsm[wn + j * 16 + fr][fc * 8];
        #pragma unroll
        for (int i = 0; i < 4; ++i)
            #pragma unroll
            for (int j = 0; j < 4; ++j)
                acc[i][j] = __builtin_amdgcn_mfma_f32_16x16x32_bf16(
                    af[i], bfr[j], acc[i][j], 0, 0, 0);
    }

    // ---- epilogue: C/D layout col=lane&15, row=(lane>>4)*4+r ----
    const int cn  = lane & 15;
    const int cr4 = (lane >> 4) * 4;
    #pragma unroll
    for (int j = 0; j < 4; ++j) {
        const int col = n0 + wn + j * 16 + cn;
        const float bv = bias[col];
        #pragma unroll
        for (int i = 0; i < 4; ++i) {
            const int row = m0 + wm + i * 16 + cr4;
            #pragma unroll
            for (int r = 0; r < 4; ++r)
                out[(size_t)(row + r) * N_DIM + col] = acc[i][j][r] + bv;
        }
    }
}

extern "C" void kernel_launch(void* const* d_in, const int* in_sizes, int n_in,
                              void* d_out, int out_size, void* d_ws, size_t ws_size,
                              hipStream_t stream) {
    const float* x    = (const float*)d_in[0];
    const int*   qw   = (const int*)d_in[1];
    const int*   qz   = (const int*)d_in[2];
    const float* sc   = (const float*)d_in[3];
    const float* bias = (const float*)d_in[4];
    float* out = (float*)d_out;

    const int M = in_sizes[0] / K_DIM;   // 4096
    dim3 grid(N_DIM / BN, M / BM);       // (86, 32)
    gptq_gemm_kernel<<<grid, dim3(256), 0, stream>>>(x, qw, qz, sc, bias, out);
}